// Round 1
// baseline (106.033 us; speedup 1.0000x reference)
//
#include <hip/hip_runtime.h>

// NEmbedding: out[b,f,e] = relu( sum_n enc[b,f,n] * W[f,n,e] + bias[f,e] )
// enc[n] = (x - bins[n]) * g[n] for all n except the single containing bin k,
// where enc[k] = 1.  g[n] = 1/(hi[n]-lo[n]), hi[n] = bins[n+1] (or -1.0 at n=63).
// => out = relu( x*P[f,e] + R[f,e] + (1 - (x-bins[k])*g[k]) * W[f,k,e] )
//    P[f,e] = sum_n g[f,n] W[f,n,e];  R[f,e] = bias[f,e] - sum_n bins[f,n] g[f,n] W[f,n,e]
// k = largest n with bins[f,n] <= x (0 if none) -- verified equivalent to the
// reference's where(left != right, v, where(left, 0, 1)) logic for sorted bins.

#define FDIM 64
#define NB   64
#define EDIM 32
#define BT   16   // b-rows per block

__global__ __launch_bounds__(64) void prep_kernel(
    const float* __restrict__ bins, const float* __restrict__ W,
    const float* __restrict__ bias,
    float* __restrict__ g, float* __restrict__ P, float* __restrict__ R)
{
    const int f = blockIdx.x;
    const int t = threadIdx.x;
    __shared__ float sg[NB];
    __shared__ float sb[NB];

    float lo = bins[f * NB + t];
    float hi = (t < NB - 1) ? bins[f * NB + t + 1] : -1.0f;
    float gv = 1.0f / (hi - lo);
    g[f * NB + t] = gv;
    sg[t] = gv;
    sb[t] = lo;
    __syncthreads();

    if (t < EDIM) {
        float p = 0.0f, q = 0.0f;
        const float* Wf = W + (size_t)f * NB * EDIM + t;
        #pragma unroll
        for (int n = 0; n < NB; ++n) {
            float w = Wf[n * EDIM];
            p = fmaf(sg[n], w, p);
            q = fmaf(sb[n] * sg[n], w, q);
        }
        P[f * EDIM + t] = p;
        R[f * EDIM + t] = bias[f * EDIM + t] - q;
    }
}

__global__ __launch_bounds__(256) void nemb_kernel(
    const float* __restrict__ x, const float* __restrict__ bins,
    const float* __restrict__ W, const float* __restrict__ g,
    const float* __restrict__ P, const float* __restrict__ R,
    float* __restrict__ out)
{
    // Padded bins rows (65) -> binary-search reads land on distinct banks per f.
    __shared__ float sBins[FDIM * (NB + 1)];
    __shared__ float sX[BT * FDIM];
    __shared__ float sC[BT * FDIM];
    __shared__ int   sK[BT * FDIM];

    const int t  = threadIdx.x;
    const long b0 = (long)blockIdx.x * BT;

    // ---- Phase 1: stage bins (4096 floats) into padded LDS, stage x tile ----
    #pragma unroll
    for (int i = 0; i < 4; ++i) {
        int li = i * 256 + t;                 // float4 index
        float4 v = reinterpret_cast<const float4*>(bins)[li];
        int el = li * 4;
        int f = el >> 6, n = el & 63;         // n % 4 == 0, no row crossing
        float* d = &sBins[f * (NB + 1) + n];
        d[0] = v.x; d[1] = v.y; d[2] = v.z; d[3] = v.w;
    }
    reinterpret_cast<float4*>(sX)[t] =
        reinterpret_cast<const float4*>(x + b0 * FDIM)[t];

    // Hoist this thread's P/R fragments (fixed (f, e-quad) across all b rows).
    const int fA = t >> 3;            // pass 0: f in 0..31
    const int fB = 32 + (t >> 3);     // pass 1: f in 32..63
    const int e0 = (t & 7) * 4;
    const float4 PA = *reinterpret_cast<const float4*>(P + fA * EDIM + e0);
    const float4 RA = *reinterpret_cast<const float4*>(R + fA * EDIM + e0);
    const float4 PB = *reinterpret_cast<const float4*>(P + fB * EDIM + e0);
    const float4 RB = *reinterpret_cast<const float4*>(R + fB * EDIM + e0);

    __syncthreads();

    // ---- Phase 2: per-(b,f) binary search; write (k, c) to LDS ----
    {
        const int f2  = t & 63;
        const int bi0 = t >> 6;               // 0..3
        const float* bl = &sBins[f2 * (NB + 1)];
        const float* gf = g + f2 * NB;
        #pragma unroll
        for (int i = 0; i < 4; ++i) {
            int bi = bi0 + 4 * i;             // covers 0..15
            float xv = sX[bi * FDIM + f2];
            int k = (bl[32] <= xv) ? 32 : 0;
            if (bl[k + 16] <= xv) k += 16;
            if (bl[k +  8] <= xv) k +=  8;
            if (bl[k +  4] <= xv) k +=  4;
            if (bl[k +  2] <= xv) k +=  2;
            if (bl[k +  1] <= xv) k +=  1;
            float c = 1.0f - (xv - bl[k]) * gf[k];
            sC[bi * FDIM + f2] = c;
            sK[bi * FDIM + f2] = k;
        }
    }
    __syncthreads();

    // ---- Phase 3: emit outputs, fully contiguous 1KB/wave float4 stores ----
    float* ob = out + b0 * (FDIM * EDIM);
    #pragma unroll 4
    for (int bi = 0; bi < BT; ++bi) {
        float xA = sX[bi * FDIM + fA];
        float cA = sC[bi * FDIM + fA];
        int   kA = sK[bi * FDIM + fA];
        float xB = sX[bi * FDIM + fB];
        float cB = sC[bi * FDIM + fB];
        int   kB = sK[bi * FDIM + fB];

        float4 wA = *reinterpret_cast<const float4*>(W + ((fA * NB + kA) * EDIM) + e0);
        float4 wB = *reinterpret_cast<const float4*>(W + ((fB * NB + kB) * EDIM) + e0);

        float4 oA, oB;
        oA.x = fmaxf(fmaf(cA, wA.x, fmaf(xA, PA.x, RA.x)), 0.0f);
        oA.y = fmaxf(fmaf(cA, wA.y, fmaf(xA, PA.y, RA.y)), 0.0f);
        oA.z = fmaxf(fmaf(cA, wA.z, fmaf(xA, PA.z, RA.z)), 0.0f);
        oA.w = fmaxf(fmaf(cA, wA.w, fmaf(xA, PA.w, RA.w)), 0.0f);
        oB.x = fmaxf(fmaf(cB, wB.x, fmaf(xB, PB.x, RB.x)), 0.0f);
        oB.y = fmaxf(fmaf(cB, wB.y, fmaf(xB, PB.y, RB.y)), 0.0f);
        oB.z = fmaxf(fmaf(cB, wB.z, fmaf(xB, PB.z, RB.z)), 0.0f);
        oB.w = fmaxf(fmaf(cB, wB.w, fmaf(xB, PB.w, RB.w)), 0.0f);

        float4* orow = reinterpret_cast<float4*>(ob + (long)bi * (FDIM * EDIM));
        orow[t]       = oA;
        orow[256 + t] = oB;
    }
}

extern "C" void kernel_launch(void* const* d_in, const int* in_sizes, int n_in,
                              void* d_out, int out_size, void* d_ws, size_t ws_size,
                              hipStream_t stream) {
    const float* x    = (const float*)d_in[0];   // (B, F)
    const float* bins = (const float*)d_in[1];   // (F, NB) sorted rows
    const float* W    = (const float*)d_in[2];   // (F, NB, E)
    const float* bias = (const float*)d_in[3];   // (F, E)
    float* out = (float*)d_out;

    // workspace layout: g (F*NB) | P (F*E) | R (F*E)  -> 32 KB total
    float* g = (float*)d_ws;
    float* P = g + FDIM * NB;
    float* R = P + FDIM * EDIM;

    const int B = in_sizes[0] / FDIM;

    prep_kernel<<<FDIM, 64, 0, stream>>>(bins, W, bias, g, P, R);
    nemb_kernel<<<B / BT, 256, 0, stream>>>(x, bins, W, g, P, R, out);
}

// Round 3
// 63.723 us; speedup vs baseline: 1.6640x; 1.6640x over previous
//
#include <hip/hip_runtime.h>

// NEmbedding: out[b,f,e] = relu( sum_n enc[b,f,n] * W[f,n,e] + bias[f,e] )
// enc[n] = (x - bins[n]) * g[n] for all n except the single containing bin k,
// where enc[k] = 1.  g[n] = 1/(hi[n]-lo[n]), hi[n] = bins[n+1] (or -1.0 at n=63).
// => out = relu( x*P[f,e] + R[f,e] + (1 - (x-bins[k])*g[k]) * W[f,k,e] )
//    P[f,e] = sum_n g[f,n] W[f,n,e];  R[f,e] = bias[f,e] - sum_n bins[f,n] g[f,n] W[f,n,e]
// k = largest n with bins[f,n] <= x (0 if none) -- verified equivalent to the
// reference's where(left != right, v, where(left, 0, 1)) logic for sorted bins.
//
// R1: output stores are nontemporal (don't thrash L2/L3 holding the 512KB W
// table); x loads nontemporal (read-once). Phase 3 batches 4 b-rows: all W
// gathers issued before any store, so the s_waitcnt consuming the loads does
// not force draining the store queue (vmcnt retires in issue order).
// R2: nontemporal builtins need clang native vectors (ext_vector_type), not
// HIP_vector_type — f32x4 replaces float4 on those paths.

#define FDIM 64
#define NB   64
#define EDIM 32
#define BT   16   // b-rows per block

typedef __attribute__((ext_vector_type(4))) float f32x4;

__global__ __launch_bounds__(64) void prep_kernel(
    const float* __restrict__ bins, const float* __restrict__ W,
    const float* __restrict__ bias,
    float* __restrict__ g, float* __restrict__ P, float* __restrict__ R)
{
    const int f = blockIdx.x;
    const int t = threadIdx.x;
    __shared__ float sg[NB];
    __shared__ float sb[NB];

    float lo = bins[f * NB + t];
    float hi = (t < NB - 1) ? bins[f * NB + t + 1] : -1.0f;
    float gv = 1.0f / (hi - lo);
    g[f * NB + t] = gv;
    sg[t] = gv;
    sb[t] = lo;
    __syncthreads();

    if (t < EDIM) {
        float p = 0.0f, q = 0.0f;
        const float* Wf = W + (size_t)f * NB * EDIM + t;
        #pragma unroll
        for (int n = 0; n < NB; ++n) {
            float w = Wf[n * EDIM];
            p = fmaf(sg[n], w, p);
            q = fmaf(sb[n] * sg[n], w, q);
        }
        P[f * EDIM + t] = p;
        R[f * EDIM + t] = bias[f * EDIM + t] - q;
    }
}

__global__ __launch_bounds__(256) void nemb_kernel(
    const float* __restrict__ x, const float* __restrict__ bins,
    const float* __restrict__ W, const float* __restrict__ g,
    const float* __restrict__ P, const float* __restrict__ R,
    float* __restrict__ out)
{
    // Padded bins rows (65) -> binary-search reads land on distinct banks per f.
    __shared__ float sBins[FDIM * (NB + 1)];
    __shared__ float sX[BT * FDIM];
    __shared__ float sC[BT * FDIM];
    __shared__ int   sK[BT * FDIM];

    const int t  = threadIdx.x;
    const long b0 = (long)blockIdx.x * BT;

    // ---- Phase 1: stage bins (4096 floats) into padded LDS, stage x tile ----
    #pragma unroll
    for (int i = 0; i < 4; ++i) {
        int li = i * 256 + t;                 // float4 index
        f32x4 v = reinterpret_cast<const f32x4*>(bins)[li];
        int el = li * 4;
        int f = el >> 6, n = el & 63;         // n % 4 == 0, no row crossing
        float* d = &sBins[f * (NB + 1) + n];
        d[0] = v.x; d[1] = v.y; d[2] = v.z; d[3] = v.w;
    }
    reinterpret_cast<f32x4*>(sX)[t] =
        __builtin_nontemporal_load(reinterpret_cast<const f32x4*>(x + b0 * FDIM) + t);

    // Hoist this thread's P/R fragments (fixed (f, e-quad) across all b rows).
    const int fA = t >> 3;            // pass 0: f in 0..31
    const int fB = 32 + (t >> 3);     // pass 1: f in 32..63
    const int e0 = (t & 7) * 4;
    const f32x4 PA = *reinterpret_cast<const f32x4*>(P + fA * EDIM + e0);
    const f32x4 RA = *reinterpret_cast<const f32x4*>(R + fA * EDIM + e0);
    const f32x4 PB = *reinterpret_cast<const f32x4*>(P + fB * EDIM + e0);
    const f32x4 RB = *reinterpret_cast<const f32x4*>(R + fB * EDIM + e0);

    __syncthreads();

    // ---- Phase 2: per-(b,f) binary search; write (k, c) to LDS ----
    {
        const int f2  = t & 63;
        const int bi0 = t >> 6;               // 0..3
        const float* bl = &sBins[f2 * (NB + 1)];
        const float* gf = g + f2 * NB;
        #pragma unroll
        for (int i = 0; i < 4; ++i) {
            int bi = bi0 + 4 * i;             // covers 0..15
            float xv = sX[bi * FDIM + f2];
            int k = (bl[32] <= xv) ? 32 : 0;
            if (bl[k + 16] <= xv) k += 16;
            if (bl[k +  8] <= xv) k +=  8;
            if (bl[k +  4] <= xv) k +=  4;
            if (bl[k +  2] <= xv) k +=  2;
            if (bl[k +  1] <= xv) k +=  1;
            float c = 1.0f - (xv - bl[k]) * gf[k];
            sC[bi * FDIM + f2] = c;
            sK[bi * FDIM + f2] = k;
        }
    }
    __syncthreads();

    // ---- Phase 3: batches of 4 b-rows; all loads issued before any store ----
    float* ob = out + b0 * (FDIM * EDIM);
    #pragma unroll
    for (int q = 0; q < 4; ++q) {
        float xA[4], cA[4], xB[4], cB[4];
        f32x4 wA[4], wB[4];
        #pragma unroll
        for (int j = 0; j < 4; ++j) {
            int bi = q * 4 + j;
            xA[j] = sX[bi * FDIM + fA];
            cA[j] = sC[bi * FDIM + fA];
            int kA = sK[bi * FDIM + fA];
            xB[j] = sX[bi * FDIM + fB];
            cB[j] = sC[bi * FDIM + fB];
            int kB = sK[bi * FDIM + fB];
            wA[j] = *reinterpret_cast<const f32x4*>(W + ((fA * NB + kA) * EDIM) + e0);
            wB[j] = *reinterpret_cast<const f32x4*>(W + ((fB * NB + kB) * EDIM) + e0);
        }
        #pragma unroll
        for (int j = 0; j < 4; ++j) {
            int bi = q * 4 + j;
            f32x4 oA, oB;
            oA.x = fmaxf(fmaf(cA[j], wA[j].x, fmaf(xA[j], PA.x, RA.x)), 0.0f);
            oA.y = fmaxf(fmaf(cA[j], wA[j].y, fmaf(xA[j], PA.y, RA.y)), 0.0f);
            oA.z = fmaxf(fmaf(cA[j], wA[j].z, fmaf(xA[j], PA.z, RA.z)), 0.0f);
            oA.w = fmaxf(fmaf(cA[j], wA[j].w, fmaf(xA[j], PA.w, RA.w)), 0.0f);
            oB.x = fmaxf(fmaf(cB[j], wB[j].x, fmaf(xB[j], PB.x, RB.x)), 0.0f);
            oB.y = fmaxf(fmaf(cB[j], wB[j].y, fmaf(xB[j], PB.y, RB.y)), 0.0f);
            oB.z = fmaxf(fmaf(cB[j], wB[j].z, fmaf(xB[j], PB.z, RB.z)), 0.0f);
            oB.w = fmaxf(fmaf(cB[j], wB[j].w, fmaf(xB[j], PB.w, RB.w)), 0.0f);

            f32x4* orow = reinterpret_cast<f32x4*>(ob + (long)bi * (FDIM * EDIM));
            __builtin_nontemporal_store(oA, orow + t);
            __builtin_nontemporal_store(oB, orow + 256 + t);
        }
    }
}

extern "C" void kernel_launch(void* const* d_in, const int* in_sizes, int n_in,
                              void* d_out, int out_size, void* d_ws, size_t ws_size,
                              hipStream_t stream) {
    const float* x    = (const float*)d_in[0];   // (B, F)
    const float* bins = (const float*)d_in[1];   // (F, NB) sorted rows
    const float* W    = (const float*)d_in[2];   // (F, NB, E)
    const float* bias = (const float*)d_in[3];   // (F, E)
    float* out = (float*)d_out;

    // workspace layout: g (F*NB) | P (F*E) | R (F*E)  -> 32 KB total
    float* g = (float*)d_ws;
    float* P = g + FDIM * NB;
    float* R = P + FDIM * EDIM;

    const int B = in_sizes[0] / FDIM;

    prep_kernel<<<FDIM, 64, 0, stream>>>(bins, W, bias, g, P, R);
    nemb_kernel<<<B / BT, 256, 0, stream>>>(x, bins, W, g, P, R, out);
}